// Round 4
// baseline (372.634 us; speedup 1.0000x reference)
//
#include <hip/hip_runtime.h>
#include <hip/hip_bf16.h>
#include <hip/hip_fp16.h>

// ---------------- helpers ----------------
static __device__ __forceinline__ float bf2f_lo(unsigned u) {
    return __uint_as_float(u << 16);
}
static __device__ __forceinline__ float bf2f_hi(unsigned u) {
    return __uint_as_float(u & 0xffff0000u);
}
static __device__ __forceinline__ unsigned f2bf_rne_bits(float f) {
    unsigned u = __float_as_uint(f);
    return u + 0x7fffu + ((u >> 16) & 1u);
}
static __device__ __forceinline__ unsigned pack_bf2(float a, float b) {
    return (f2bf_rne_bits(a) >> 16) | (f2bf_rne_bits(b) & 0xffff0000u);
}
static __device__ __forceinline__ float pfun(float e) {
    e = fmaxf(e, 0.2f * e);   // leaky_relu(0.2): valid for both signs
    return __expf(e);         // |e| small -> no max-subtraction needed
}

// ================= CSR build: two-level bucket sort =================
#define CHUNK 4096

__global__ void kb_zero(int* bucketCount, int NBK) {
    int i = blockIdx.x * 256 + threadIdx.x;
    if (i < NBK) bucketCount[i] = 0;
}

__global__ void kb_count(const int* __restrict__ dst, int* bucketCount,
                         int E, int T, int NBK) {
    __shared__ int cnt[256];
    const int tid = threadIdx.x;
    const int beg = blockIdx.x * CHUNK;
    const int end = min(beg + CHUNK, T);
    cnt[tid] = 0;
    __syncthreads();
    for (int i = beg + tid; i < end; i += 256) {
        int d = (i < E) ? dst[i] : (i - E);
        atomicAdd(&cnt[d >> 8], 1);
    }
    __syncthreads();
    if (tid < NBK && cnt[tid] > 0) atomicAdd(&bucketCount[tid], cnt[tid]);
}

__global__ void kb_scan(const int* __restrict__ bucketCount, int* bucketBase,
                        int* bucketCursor, int* row_ptr, int NBK, int N, int total) {
    __shared__ int sm[256];
    const int tid = threadIdx.x;
    int v = (tid < NBK) ? bucketCount[tid] : 0;
    sm[tid] = v;
    __syncthreads();
    for (int off = 1; off < 256; off <<= 1) {
        int t = (tid >= off) ? sm[tid - off] : 0;
        __syncthreads();
        sm[tid] += t;
        __syncthreads();
    }
    if (tid < NBK) {
        int ex = sm[tid] - v;
        bucketBase[tid] = ex;
        bucketCursor[tid] = ex;
    }
    if (tid == 0) {
        bucketBase[NBK] = total;
        row_ptr[N] = total;
    }
}

__global__ void kb_place(const int* __restrict__ src, const int* __restrict__ dst,
                         int* bucketCursor, unsigned* __restrict__ barr,
                         int E, int T, int NBK) {
    __shared__ int cnt[256];
    __shared__ int wb[256];
    const int tid = threadIdx.x;
    const int beg = blockIdx.x * CHUNK;
    const int end = min(beg + CHUNK, T);
    cnt[tid] = 0;
    __syncthreads();
    for (int i = beg + tid; i < end; i += 256) {
        int d = (i < E) ? dst[i] : (i - E);
        atomicAdd(&cnt[d >> 8], 1);
    }
    __syncthreads();
    if (tid < NBK) {
        int c = cnt[tid];
        wb[tid] = (c > 0) ? atomicAdd(&bucketCursor[tid], c) : 0;
    }
    __syncthreads();
    cnt[tid] = 0;
    __syncthreads();
    for (int i = beg + tid; i < end; i += 256) {
        int s, d;
        if (i < E) { s = src[i]; d = dst[i]; }
        else       { s = i - E;  d = s; }
        int g = d >> 8;
        unsigned pk = (unsigned)s | ((unsigned)(d & 255) << 16);
        int r = atomicAdd(&cnt[g], 1);
        barr[wb[g] + r] = pk;
    }
}

__global__ void kb_csr(const unsigned* __restrict__ barr, const int* __restrict__ bucketBase,
                       int* __restrict__ row_ptr, int* __restrict__ col, int N) {
    __shared__ int cnt[256];
    __shared__ int sm[256];
    __shared__ int cur[256];
    const int tid = threadIdx.x;
    const int b = blockIdx.x;
    const int beg = bucketBase[b];
    const int end = bucketBase[b + 1];
    cnt[tid] = 0;
    __syncthreads();
    for (int i = beg + tid; i < end; i += 256)
        atomicAdd(&cnt[barr[i] >> 16], 1);
    __syncthreads();
    int v = cnt[tid];
    sm[tid] = v;
    __syncthreads();
    for (int off = 1; off < 256; off <<= 1) {
        int t = (tid >= off) ? sm[tid - off] : 0;
        __syncthreads();
        sm[tid] += t;
        __syncthreads();
    }
    int ex = sm[tid] - v;
    int n = b * 256 + tid;
    if (n < N) row_ptr[n] = beg + ex;
    cur[tid] = beg + ex;
    __syncthreads();
    for (int i = beg + tid; i < end; i += 256) {
        unsigned p = barr[i];
        int pos = atomicAdd(&cur[p >> 16], 1);
        col[pos] = (int)(p & 0xFFFFu);
    }
}

// ---------------- GEMM: h = A @ W (fp32 in, bf16 out) + alpha epilogue ----------------
#define KC 32
__launch_bounds__(512, 1)
__global__ void k_gemm(const float* __restrict__ A, const float* __restrict__ W,
                       const float* __restrict__ a_src, const float* __restrict__ a_dst,
                       unsigned* __restrict__ Hout,
                       float* __restrict__ asrc_o, float* __restrict__ adst_o,
                       int nrows) {
    __shared__ float Wl[KC * 128];        // 16 KB
    __shared__ float Xl[128 * (KC + 4)];  // 18 KB, padded stride 36 (2-way bank = free)
    const int tid = threadIdx.x;
    const int tx = tid & 15;   // col group: cols 8*tx .. 8*tx+7
    const int ty = tid >> 4;   // row group: rows 4*ty .. 4*ty+3
    const int row0 = blockIdx.x * 128;

    float acc[4][8];
#pragma unroll
    for (int i = 0; i < 4; i++)
#pragma unroll
        for (int j = 0; j < 8; j++) acc[i][j] = 0.f;

    for (int kc = 0; kc < 128; kc += KC) {
#pragma unroll
        for (int it = 0; it < 2; ++it) {
            int ff = it * 512 + tid;
            int r = ff >> 5, cq = ff & 31;
            *(float4*)&Wl[r * 128 + cq * 4] = *(const float4*)&W[(size_t)(kc + r) * 128 + cq * 4];
        }
#pragma unroll
        for (int it = 0; it < 2; ++it) {
            int ff = it * 512 + tid;
            int r = ff >> 3, kq = ff & 7;
            int gr = row0 + r;
            float4 v = make_float4(0.f, 0.f, 0.f, 0.f);
            if (gr < nrows) v = *(const float4*)&A[(size_t)gr * 128 + kc + kq * 4];
            *(float4*)&Xl[r * (KC + 4) + kq * 4] = v;
        }
        __syncthreads();
#pragma unroll
        for (int k0 = 0; k0 < KC; k0 += 4) {
            float4 xv[4];
#pragma unroll
            for (int i = 0; i < 4; i++)
                xv[i] = *(float4*)&Xl[(4 * ty + i) * (KC + 4) + k0];
            const float* xp = (const float*)xv;
#pragma unroll
            for (int kk = 0; kk < 4; ++kk) {
                float4 w0 = *(float4*)&Wl[(k0 + kk) * 128 + 8 * tx];
                float4 w1 = *(float4*)&Wl[(k0 + kk) * 128 + 8 * tx + 4];
#pragma unroll
                for (int i = 0; i < 4; i++) {
                    float xs = xp[i * 4 + kk];
                    acc[i][0] += xs * w0.x; acc[i][1] += xs * w0.y;
                    acc[i][2] += xs * w0.z; acc[i][3] += xs * w0.w;
                    acc[i][4] += xs * w1.x; acc[i][5] += xs * w1.y;
                    acc[i][6] += xs * w1.z; acc[i][7] += xs * w1.w;
                }
            }
        }
        __syncthreads();
    }

    const int head = tx >> 2;
    const int c0 = 8 * tx;
    float as_c[8], ad_c[8];
#pragma unroll
    for (int j = 0; j < 8; j++) { as_c[j] = a_src[c0 + j]; ad_c[j] = a_dst[c0 + j]; }
#pragma unroll
    for (int i = 0; i < 4; i++) {
        int gr = row0 + 4 * ty + i;
        float ps = 0.f, pd = 0.f;
#pragma unroll
        for (int j = 0; j < 8; j++) { ps += acc[i][j] * as_c[j]; pd += acc[i][j] * ad_c[j]; }
        ps += __shfl_xor(ps, 1); ps += __shfl_xor(ps, 2);
        pd += __shfl_xor(pd, 1); pd += __shfl_xor(pd, 2);
        if (gr < nrows) {
            if ((tx & 3) == 0) {
                asrc_o[(size_t)gr * 4 + head] = ps;
                adst_o[(size_t)gr * 4 + head] = pd;
            }
            uint4 o;
            o.x = pack_bf2(acc[i][0], acc[i][1]);
            o.y = pack_bf2(acc[i][2], acc[i][3]);
            o.z = pack_bf2(acc[i][4], acc[i][5]);
            o.w = pack_bf2(acc[i][6], acc[i][7]);
            *(uint4*)&Hout[(size_t)gr * 64 + 4 * tx] = o;
        }
    }
}

// ---------------- per-edge attention: alpha = softmax(leaky(asrc+adst)) ----------------
// One wave per dst node, one LANE per edge (kills the 16x-redundant e/p compute).
// Butterfly-reduces sum(p) per head across 64 lanes; stores pre-normalized
// alpha as fp16 in transposed [H][T] layout (CSR edge order -> contiguous).
__launch_bounds__(256)
__global__ void k_edge(const float* __restrict__ asrc, const float* __restrict__ adst,
                       const int* __restrict__ row_ptr, const int* __restrict__ col,
                       __half* __restrict__ alpha_t, int N, int T) {
    const int wv = (blockIdx.x * 256 + threadIdx.x) >> 6;  // wave id = dst node
    const int lane = threadIdx.x & 63;
    if (wv >= N) return;  // wave-uniform exit
    const int beg = row_ptr[wv];
    const int cnt = row_ptr[wv + 1] - beg;
    const float4 ad = *(const float4*)&adst[(size_t)wv * 4];

    float4 sp = make_float4(0.f, 0.f, 0.f, 0.f);
    float4 p0 = make_float4(0.f, 0.f, 0.f, 0.f);
    for (int base = 0; base < cnt; base += 64) {
        float4 p = make_float4(0.f, 0.f, 0.f, 0.f);
        if (base + lane < cnt) {
            int s = col[beg + base + lane];
            float4 av = *(const float4*)&asrc[(size_t)s * 4];
            p.x = pfun(av.x + ad.x);
            p.y = pfun(av.y + ad.y);
            p.z = pfun(av.z + ad.z);
            p.w = pfun(av.w + ad.w);
        }
        if (base == 0) p0 = p;
        sp.x += p.x; sp.y += p.y; sp.z += p.z; sp.w += p.w;
    }
#pragma unroll
    for (int off = 1; off < 64; off <<= 1) {
        sp.x += __shfl_xor(sp.x, off);
        sp.y += __shfl_xor(sp.y, off);
        sp.z += __shfl_xor(sp.z, off);
        sp.w += __shfl_xor(sp.w, off);
    }
    float4 inv = make_float4(1.f / sp.x, 1.f / sp.y, 1.f / sp.z, 1.f / sp.w);

    for (int base = 0; base < cnt; base += 64) {
        if (base + lane < cnt) {
            int j = beg + base + lane;
            float4 p;
            if (base == 0) {
                p = p0;
            } else {
                int s = col[j];
                float4 av = *(const float4*)&asrc[(size_t)s * 4];
                p.x = pfun(av.x + ad.x);
                p.y = pfun(av.y + ad.y);
                p.z = pfun(av.z + ad.z);
                p.w = pfun(av.w + ad.w);
            }
            alpha_t[(size_t)0 * T + j] = __float2half(p.x * inv.x);
            alpha_t[(size_t)1 * T + j] = __float2half(p.y * inv.y);
            alpha_t[(size_t)2 * T + j] = __float2half(p.z * inv.z);
            alpha_t[(size_t)3 * T + j] = __float2half(p.w * inv.w);
        }
    }
}

// ---------------- aggregate: out[d] = sum alpha * h[src]; + bias + ELU ----------------
// One wave per dst; lane l owns channels 2l,2l+1 (head = l>>4). alpha is
// precomputed & pre-normalized -> inner loop is pure gather-FMA (~8 slots/edge).
#define UAG 8
__launch_bounds__(256)
__global__ void k_aggr(const unsigned* __restrict__ h,  // bf16 pairs, N*64
                       const __half* __restrict__ alpha_t,
                       const float* __restrict__ bias,
                       const int* __restrict__ row_ptr, const int* __restrict__ col,
                       float* __restrict__ out, int N, int T) {
    const int lane = threadIdx.x & 63;
    const int d = blockIdx.x * 4 + (threadIdx.x >> 6);
    if (d >= N) return;
    const int hd = lane >> 4;
    const __half* at = alpha_t + (size_t)hd * T;
    const int beg = row_ptr[d];
    const int end = row_ptr[d + 1];

    float ac0[2] = {0.f, 0.f}, ac1[2] = {0.f, 0.f};
    int j = beg;
    for (; j + UAG <= end; j += UAG) {
        int s[UAG];
#pragma unroll
        for (int k = 0; k < UAG; ++k) s[k] = col[j + k];
        float af[UAG];
        unsigned uv[UAG];
#pragma unroll
        for (int k = 0; k < UAG; ++k) {
            af[k] = __half2float(at[j + k]);
            uv[k] = h[(size_t)s[k] * 64 + lane];
        }
#pragma unroll
        for (int k = 0; k < UAG; ++k) {
            ac0[k & 1] += af[k] * bf2f_lo(uv[k]);
            ac1[k & 1] += af[k] * bf2f_hi(uv[k]);
        }
    }
    for (; j < end; ++j) {
        int s = col[j];
        float a = __half2float(at[j]);
        unsigned u = h[(size_t)s * 64 + lane];
        ac0[0] += a * bf2f_lo(u);
        ac1[0] += a * bf2f_hi(u);
    }
    float acc0 = ac0[0] + ac0[1];
    float acc1 = ac1[0] + ac1[1];

    int c = 2 * lane;
    float v0 = acc0 + bias[c];
    float v1 = acc1 + bias[c + 1];
    v0 = (v0 > 0.f) ? v0 : (__expf(v0) - 1.f);    // ELU
    v1 = (v1 > 0.f) ? v1 : (__expf(v1) - 1.f);
    *(float2*)&out[(size_t)d * 128 + c] = make_float2(v0, v1);
}

// ---------------- launch ----------------
extern "C" void kernel_launch(void* const* d_in, const int* in_sizes, int n_in,
                              void* d_out, int out_size, void* d_ws, size_t ws_size,
                              hipStream_t stream) {
    const float* x      = (const float*)d_in[0];
    const int*   ei     = (const int*)d_in[1];
    const float* W1     = (const float*)d_in[2];
    const float* a_src1 = (const float*)d_in[3];
    const float* a_dst1 = (const float*)d_in[4];
    const float* b1     = (const float*)d_in[5];
    const float* W2     = (const float*)d_in[6];
    const float* a_src2 = (const float*)d_in[7];
    const float* a_dst2 = (const float*)d_in[8];
    const float* b2     = (const float*)d_in[9];

    const int N = in_sizes[0] / 128;
    const int E = in_sizes[1] / 2;
    const int T = E + N;                  // edges incl self-loops
    const int NBK = (N + 255) / 256;      // buckets (needs N <= 65536)
    const int* src = ei;
    const int* dst = ei + E;

    // workspace carve (256B aligned)
    char* w = (char*)d_ws;
    auto alloc = [&](size_t bytes) -> char* {
        char* p = w;
        w += (bytes + 255) & ~(size_t)255;
        return p;
    };
    unsigned* h_bf    = (unsigned*)alloc((size_t)N * 64 * 4);   // bf16 h, 12.8 MB
    float*    o1      = (float*)alloc((size_t)N * 128 * 4);     // layer-1 out, 25.6 MB
    float*    asrc    = (float*)alloc((size_t)N * 4 * 4);
    float*    adst    = (float*)alloc((size_t)N * 4 * 4);
    int*      row_ptr = (int*)alloc((size_t)(N + 1) * 4);
    int*      col     = (int*)alloc((size_t)T * 4);             // 6.6 MB
    __half*   alpha_t = (__half*)alloc((size_t)T * 4 * 2);      // [H][T] fp16, 13.4 MB
    int*      bCount  = (int*)alloc((size_t)NBK * 4);
    int*      bBase   = (int*)alloc((size_t)(NBK + 1) * 4);
    int*      bCursor = (int*)alloc((size_t)NBK * 4);
    // bucketArray aliases o1: only live during CSR build, o1 written later.
    unsigned* barr    = (unsigned*)o1;
    (void)ws_size; (void)n_in; (void)out_size;

    const int PB = (T + CHUNK - 1) / CHUNK;

    // CSR build (shared by both layers) — no per-edge global atomics
    hipLaunchKernelGGL(kb_zero, dim3((NBK + 255) / 256), dim3(256), 0, stream, bCount, NBK);
    hipLaunchKernelGGL(kb_count, dim3(PB), dim3(256), 0, stream, dst, bCount, E, T, NBK);
    hipLaunchKernelGGL(kb_scan, dim3(1), dim3(256), 0, stream, bCount, bBase, bCursor, row_ptr, NBK, N, T);
    hipLaunchKernelGGL(kb_place, dim3(PB), dim3(256), 0, stream, src, dst, bCursor, barr, E, T, NBK);
    hipLaunchKernelGGL(kb_csr, dim3(NBK), dim3(256), 0, stream, barr, bBase, row_ptr, col, N);

    const int GB = (N + 127) / 128;       // gemm blocks
    const int AB = (N + 3) / 4;           // aggr blocks (4 waves/block)
    const int EB = (N * 64 + 255) / 256;  // k_edge blocks (wave per node)

    // layer 1
    hipLaunchKernelGGL(k_gemm, dim3(GB), dim3(512), 0, stream, x, W1, a_src1, a_dst1, h_bf, asrc, adst, N);
    hipLaunchKernelGGL(k_edge, dim3(EB), dim3(256), 0, stream, asrc, adst, row_ptr, col, alpha_t, N, T);
    hipLaunchKernelGGL(k_aggr, dim3(AB), dim3(256), 0, stream, h_bf, alpha_t, b1, row_ptr, col, o1, N, T);
    // layer 2
    hipLaunchKernelGGL(k_gemm, dim3(GB), dim3(512), 0, stream, o1, W2, a_src2, a_dst2, h_bf, asrc, adst, N);
    hipLaunchKernelGGL(k_edge, dim3(EB), dim3(256), 0, stream, asrc, adst, row_ptr, col, alpha_t, N, T);
    hipLaunchKernelGGL(k_aggr, dim3(AB), dim3(256), 0, stream, h_bf, alpha_t, b2, row_ptr, col, (float*)d_out, N, T);
}

// Round 5
// 329.205 us; speedup vs baseline: 1.1319x; 1.1319x over previous
//
#include <hip/hip_runtime.h>
#include <hip/hip_bf16.h>

// ---------------- helpers ----------------
static __device__ __forceinline__ float bf2f_lo(unsigned u) {
    return __uint_as_float(u << 16);
}
static __device__ __forceinline__ float bf2f_hi(unsigned u) {
    return __uint_as_float(u & 0xffff0000u);
}
static __device__ __forceinline__ unsigned f2bf_rne_bits(float f) {
    unsigned u = __float_as_uint(f);
    return u + 0x7fffu + ((u >> 16) & 1u);
}
static __device__ __forceinline__ unsigned pack_bf2(float a, float b) {
    return (f2bf_rne_bits(a) >> 16) | (f2bf_rne_bits(b) & 0xffff0000u);
}
static __device__ __forceinline__ float pfun(float e) {
    e = fmaxf(e, 0.2f * e);   // leaky_relu(0.2): valid for both signs
    return __expf(e);         // |e| small -> no max-subtraction needed
}

// ================= CSR build: two-level bucket sort =================
#define CHUNK 4096

__global__ void kb_zero(int* bucketCount, int NBK) {
    int i = blockIdx.x * 256 + threadIdx.x;
    if (i < NBK) bucketCount[i] = 0;
}

__global__ void kb_count(const int* __restrict__ dst, int* bucketCount,
                         int E, int T, int NBK) {
    __shared__ int cnt[256];
    const int tid = threadIdx.x;
    const int beg = blockIdx.x * CHUNK;
    const int end = min(beg + CHUNK, T);
    cnt[tid] = 0;
    __syncthreads();
    for (int i = beg + tid; i < end; i += 256) {
        int d = (i < E) ? dst[i] : (i - E);
        atomicAdd(&cnt[d >> 8], 1);
    }
    __syncthreads();
    if (tid < NBK && cnt[tid] > 0) atomicAdd(&bucketCount[tid], cnt[tid]);
}

__global__ void kb_scan(const int* __restrict__ bucketCount, int* bucketBase,
                        int* bucketCursor, int* row_ptr, int NBK, int N, int total) {
    __shared__ int sm[256];
    const int tid = threadIdx.x;
    int v = (tid < NBK) ? bucketCount[tid] : 0;
    sm[tid] = v;
    __syncthreads();
    for (int off = 1; off < 256; off <<= 1) {
        int t = (tid >= off) ? sm[tid - off] : 0;
        __syncthreads();
        sm[tid] += t;
        __syncthreads();
    }
    if (tid < NBK) {
        int ex = sm[tid] - v;
        bucketBase[tid] = ex;
        bucketCursor[tid] = ex;
    }
    if (tid == 0) {
        bucketBase[NBK] = total;
        row_ptr[N] = total;
    }
}

__global__ void kb_place(const int* __restrict__ src, const int* __restrict__ dst,
                         int* bucketCursor, unsigned* __restrict__ barr,
                         int E, int T, int NBK) {
    __shared__ int cnt[256];
    __shared__ int wb[256];
    const int tid = threadIdx.x;
    const int beg = blockIdx.x * CHUNK;
    const int end = min(beg + CHUNK, T);
    cnt[tid] = 0;
    __syncthreads();
    for (int i = beg + tid; i < end; i += 256) {
        int d = (i < E) ? dst[i] : (i - E);
        atomicAdd(&cnt[d >> 8], 1);
    }
    __syncthreads();
    if (tid < NBK) {
        int c = cnt[tid];
        wb[tid] = (c > 0) ? atomicAdd(&bucketCursor[tid], c) : 0;
    }
    __syncthreads();
    cnt[tid] = 0;
    __syncthreads();
    for (int i = beg + tid; i < end; i += 256) {
        int s, d;
        if (i < E) { s = src[i]; d = dst[i]; }
        else       { s = i - E;  d = s; }
        int g = d >> 8;
        unsigned pk = (unsigned)s | ((unsigned)(d & 255) << 16);
        int r = atomicAdd(&cnt[g], 1);
        barr[wb[g] + r] = pk;
    }
}

__global__ void kb_csr(const unsigned* __restrict__ barr, const int* __restrict__ bucketBase,
                       int* __restrict__ row_ptr, int* __restrict__ col, int N) {
    __shared__ int cnt[256];
    __shared__ int sm[256];
    __shared__ int cur[256];
    const int tid = threadIdx.x;
    const int b = blockIdx.x;
    const int beg = bucketBase[b];
    const int end = bucketBase[b + 1];
    cnt[tid] = 0;
    __syncthreads();
    for (int i = beg + tid; i < end; i += 256)
        atomicAdd(&cnt[barr[i] >> 16], 1);
    __syncthreads();
    int v = cnt[tid];
    sm[tid] = v;
    __syncthreads();
    for (int off = 1; off < 256; off <<= 1) {
        int t = (tid >= off) ? sm[tid - off] : 0;
        __syncthreads();
        sm[tid] += t;
        __syncthreads();
    }
    int ex = sm[tid] - v;
    int n = b * 256 + tid;
    if (n < N) row_ptr[n] = beg + ex;
    cur[tid] = beg + ex;
    __syncthreads();
    for (int i = beg + tid; i < end; i += 256) {
        unsigned p = barr[i];
        int pos = atomicAdd(&cur[p >> 16], 1);
        col[pos] = (int)(p & 0xFFFFu);
    }
}

// ---------------- GEMM: h = A @ W (fp32 in, bf16 out) + alpha epilogue ----------------
#define KC 32
__launch_bounds__(512, 1)
__global__ void k_gemm(const float* __restrict__ A, const float* __restrict__ W,
                       const float* __restrict__ a_src, const float* __restrict__ a_dst,
                       unsigned* __restrict__ Hout,
                       float* __restrict__ asrc_o, float* __restrict__ adst_o,
                       int nrows) {
    __shared__ float Wl[KC * 128];        // 16 KB
    __shared__ float Xl[128 * (KC + 4)];  // 18 KB, padded stride 36 (2-way bank = free)
    const int tid = threadIdx.x;
    const int tx = tid & 15;   // col group: cols 8*tx .. 8*tx+7
    const int ty = tid >> 4;   // row group: rows 4*ty .. 4*ty+3
    const int row0 = blockIdx.x * 128;

    float acc[4][8];
#pragma unroll
    for (int i = 0; i < 4; i++)
#pragma unroll
        for (int j = 0; j < 8; j++) acc[i][j] = 0.f;

    for (int kc = 0; kc < 128; kc += KC) {
#pragma unroll
        for (int it = 0; it < 2; ++it) {
            int ff = it * 512 + tid;
            int r = ff >> 5, cq = ff & 31;
            *(float4*)&Wl[r * 128 + cq * 4] = *(const float4*)&W[(size_t)(kc + r) * 128 + cq * 4];
        }
#pragma unroll
        for (int it = 0; it < 2; ++it) {
            int ff = it * 512 + tid;
            int r = ff >> 3, kq = ff & 7;
            int gr = row0 + r;
            float4 v = make_float4(0.f, 0.f, 0.f, 0.f);
            if (gr < nrows) v = *(const float4*)&A[(size_t)gr * 128 + kc + kq * 4];
            *(float4*)&Xl[r * (KC + 4) + kq * 4] = v;
        }
        __syncthreads();
#pragma unroll
        for (int k0 = 0; k0 < KC; k0 += 4) {
            float4 xv[4];
#pragma unroll
            for (int i = 0; i < 4; i++)
                xv[i] = *(float4*)&Xl[(4 * ty + i) * (KC + 4) + k0];
            const float* xp = (const float*)xv;
#pragma unroll
            for (int kk = 0; kk < 4; ++kk) {
                float4 w0 = *(float4*)&Wl[(k0 + kk) * 128 + 8 * tx];
                float4 w1 = *(float4*)&Wl[(k0 + kk) * 128 + 8 * tx + 4];
#pragma unroll
                for (int i = 0; i < 4; i++) {
                    float xs = xp[i * 4 + kk];
                    acc[i][0] += xs * w0.x; acc[i][1] += xs * w0.y;
                    acc[i][2] += xs * w0.z; acc[i][3] += xs * w0.w;
                    acc[i][4] += xs * w1.x; acc[i][5] += xs * w1.y;
                    acc[i][6] += xs * w1.z; acc[i][7] += xs * w1.w;
                }
            }
        }
        __syncthreads();
    }

    const int head = tx >> 2;
    const int c0 = 8 * tx;
    float as_c[8], ad_c[8];
#pragma unroll
    for (int j = 0; j < 8; j++) { as_c[j] = a_src[c0 + j]; ad_c[j] = a_dst[c0 + j]; }
#pragma unroll
    for (int i = 0; i < 4; i++) {
        int gr = row0 + 4 * ty + i;
        float ps = 0.f, pd = 0.f;
#pragma unroll
        for (int j = 0; j < 8; j++) { ps += acc[i][j] * as_c[j]; pd += acc[i][j] * ad_c[j]; }
        ps += __shfl_xor(ps, 1); ps += __shfl_xor(ps, 2);
        pd += __shfl_xor(pd, 1); pd += __shfl_xor(pd, 2);
        if (gr < nrows) {
            if ((tx & 3) == 0) {
                asrc_o[(size_t)gr * 4 + head] = ps;
                adst_o[(size_t)gr * 4 + head] = pd;
            }
            uint4 o;
            o.x = pack_bf2(acc[i][0], acc[i][1]);
            o.y = pack_bf2(acc[i][2], acc[i][3]);
            o.z = pack_bf2(acc[i][4], acc[i][5]);
            o.w = pack_bf2(acc[i][6], acc[i][7]);
            *(uint4*)&Hout[(size_t)gr * 64 + 4 * tx] = o;
        }
    }
}

// ---------------- fused softmax-aggregate + bias + ELU ----------------
// One wave per dst node; batches of 16 edges.
// Roles per lane l:  p-compute: edge slot eb=l>>2, head hp=l&3 (p computed
// ONCE per (edge,head) across the wave, not 16x redundant);
// consume: channels 2l,2l+1 of head hdc=l>>4.
// p shared to consumers via ds_bpermute (__shfl with varying index).
// h gather base made wave-uniform via readlane -> SALU addressing.
// col for batch k+1 prefetched before batch k's gathers (breaks the
// cross-iteration col->gather dependency chain).
#define BAT 16
__launch_bounds__(256)
__global__ void k_aggr(const unsigned* __restrict__ h,  // bf16 pairs, N*64
                       const float* __restrict__ asrc, const float* __restrict__ adst,
                       const float* __restrict__ bias,
                       const int* __restrict__ row_ptr, const int* __restrict__ col,
                       float* __restrict__ out, int N) {
    const int lane = threadIdx.x & 63;
    const int d = blockIdx.x * 4 + (threadIdx.x >> 6);
    if (d >= N) return;
    const int eb  = lane >> 2;   // edge slot (p-compute role)
    const int hp  = lane & 3;    // head (p-compute role)
    const int hdc = lane >> 4;   // head (consumer role)
    const float adv = adst[(size_t)d * 4 + hp];
    const int beg = row_ptr[d];
    const int end = row_ptr[d + 1];

    float ac0 = 0.f, ac1 = 0.f, sp = 0.f;

    // first col batch (lane's edge slot), 0-guarded (node 0 is valid to touch)
    int cv = 0;
    { int idx = beg + eb; if (idx < end) cv = col[idx]; }

    for (int j = beg; j < end; j += BAT) {
        // prefetch next batch's col before consuming this batch
        int cvn = 0;
        { int idx = j + BAT + eb; if (idx < end) cvn = col[idx]; }

        // p for (edge eb, head hp), masked for inactive slots
        float a = asrc[(size_t)(unsigned)cv * 4 + hp];
        float p = (j + eb < end) ? pfun(a + adv) : 0.f;
        sp += p;

        // 16 h gathers, wave-uniform row base via readlane (SALU addressing)
        unsigned u[BAT];
#pragma unroll
        for (int k = 0; k < BAT; ++k) {
            int sk = __builtin_amdgcn_readlane(cv, 4 * k);
            u[k] = h[(size_t)(unsigned)sk * 64 + lane];
        }
        // share p to consumer lanes (bpermute) + FMA
#pragma unroll
        for (int k = 0; k < BAT; ++k) {
            float pk = __shfl(p, 4 * k + hdc);
            ac0 += pk * bf2f_lo(u[k]);
            ac1 += pk * bf2f_hi(u[k]);
        }
        cv = cvn;
    }

    // reduce sp over the 16 lanes sharing head (l&3)
    sp += __shfl_xor(sp, 4);
    sp += __shfl_xor(sp, 8);
    sp += __shfl_xor(sp, 16);
    sp += __shfl_xor(sp, 32);
    float spv = __shfl(sp, hdc);   // lane 'hdc' has (l&3)==hdc
    float inv = 1.f / spv;

    int c = 2 * lane;
    float v0 = ac0 * inv + bias[c];
    float v1 = ac1 * inv + bias[c + 1];
    v0 = (v0 > 0.f) ? v0 : (__expf(v0) - 1.f);    // ELU
    v1 = (v1 > 0.f) ? v1 : (__expf(v1) - 1.f);
    *(float2*)&out[(size_t)d * 128 + c] = make_float2(v0, v1);
}

// ---------------- launch ----------------
extern "C" void kernel_launch(void* const* d_in, const int* in_sizes, int n_in,
                              void* d_out, int out_size, void* d_ws, size_t ws_size,
                              hipStream_t stream) {
    const float* x      = (const float*)d_in[0];
    const int*   ei     = (const int*)d_in[1];
    const float* W1     = (const float*)d_in[2];
    const float* a_src1 = (const float*)d_in[3];
    const float* a_dst1 = (const float*)d_in[4];
    const float* b1     = (const float*)d_in[5];
    const float* W2     = (const float*)d_in[6];
    const float* a_src2 = (const float*)d_in[7];
    const float* a_dst2 = (const float*)d_in[8];
    const float* b2     = (const float*)d_in[9];

    const int N = in_sizes[0] / 128;
    const int E = in_sizes[1] / 2;
    const int T = E + N;                  // edges incl self-loops
    const int NBK = (N + 255) / 256;      // buckets (needs N <= 65536)
    const int* src = ei;
    const int* dst = ei + E;

    // workspace carve (256B aligned)
    char* w = (char*)d_ws;
    auto alloc = [&](size_t bytes) -> char* {
        char* p = w;
        w += (bytes + 255) & ~(size_t)255;
        return p;
    };
    unsigned* h_bf    = (unsigned*)alloc((size_t)N * 64 * 4);   // bf16 h, 12.8 MB
    float*    o1      = (float*)alloc((size_t)N * 128 * 4);     // layer-1 out, 25.6 MB
    float*    asrc    = (float*)alloc((size_t)N * 4 * 4);
    float*    adst    = (float*)alloc((size_t)N * 4 * 4);
    int*      row_ptr = (int*)alloc((size_t)(N + 1) * 4);
    int*      col     = (int*)alloc((size_t)T * 4);             // 6.6 MB
    int*      bCount  = (int*)alloc((size_t)NBK * 4);
    int*      bBase   = (int*)alloc((size_t)(NBK + 1) * 4);
    int*      bCursor = (int*)alloc((size_t)NBK * 4);
    // bucketArray aliases o1: only live during CSR build, o1 written later.
    unsigned* barr    = (unsigned*)o1;
    (void)ws_size; (void)n_in; (void)out_size;

    const int PB = (T + CHUNK - 1) / CHUNK;

    // CSR build (shared by both layers) — no per-edge global atomics
    hipLaunchKernelGGL(kb_zero, dim3((NBK + 255) / 256), dim3(256), 0, stream, bCount, NBK);
    hipLaunchKernelGGL(kb_count, dim3(PB), dim3(256), 0, stream, dst, bCount, E, T, NBK);
    hipLaunchKernelGGL(kb_scan, dim3(1), dim3(256), 0, stream, bCount, bBase, bCursor, row_ptr, NBK, N, T);
    hipLaunchKernelGGL(kb_place, dim3(PB), dim3(256), 0, stream, src, dst, bCursor, barr, E, T, NBK);
    hipLaunchKernelGGL(kb_csr, dim3(NBK), dim3(256), 0, stream, barr, bBase, row_ptr, col, N);

    const int GB = (N + 127) / 128;   // gemm blocks
    const int AB = (N + 3) / 4;       // aggr blocks (4 waves/block)

    // layer 1
    hipLaunchKernelGGL(k_gemm, dim3(GB), dim3(512), 0, stream, x, W1, a_src1, a_dst1, h_bf, asrc, adst, N);
    hipLaunchKernelGGL(k_aggr, dim3(AB), dim3(256), 0, stream, h_bf, asrc, adst, b1, row_ptr, col, o1, N);
    // layer 2
    hipLaunchKernelGGL(k_gemm, dim3(GB), dim3(512), 0, stream, o1, W2, a_src2, a_dst2, h_bf, asrc, adst, N);
    hipLaunchKernelGGL(k_aggr, dim3(AB), dim3(256), 0, stream, h_bf, asrc, adst, b2, row_ptr, col, (float*)d_out, N);
}

// Round 6
// 306.999 us; speedup vs baseline: 1.2138x; 1.0723x over previous
//
#include <hip/hip_runtime.h>
#include <hip/hip_bf16.h>

typedef _Float16 half8 __attribute__((ext_vector_type(8)));
typedef float f32x4 __attribute__((ext_vector_type(4)));

// ---------------- helpers ----------------
static __device__ __forceinline__ float bf2f_lo(unsigned u) {
    return __uint_as_float(u << 16);
}
static __device__ __forceinline__ float bf2f_hi(unsigned u) {
    return __uint_as_float(u & 0xffff0000u);
}
static __device__ __forceinline__ unsigned f2bf_rne_bits(float f) {
    unsigned u = __float_as_uint(f);
    return u + 0x7fffu + ((u >> 16) & 1u);
}
static __device__ __forceinline__ unsigned pack_bf2(float a, float b) {
    return (f2bf_rne_bits(a) >> 16) | (f2bf_rne_bits(b) & 0xffff0000u);
}
static __device__ __forceinline__ float pfun(float e) {
    e = fmaxf(e, 0.2f * e);   // leaky_relu(0.2)
    return __expf(e);         // |e| small -> no max-subtraction needed
}

// ================= CSR build: two-level bucket sort =================
#define CHUNK 4096

__global__ void kb_zero(int* bucketCount, int NBK) {
    int i = blockIdx.x * 256 + threadIdx.x;
    if (i < NBK) bucketCount[i] = 0;
}

__global__ void kb_count(const int* __restrict__ dst, int* bucketCount,
                         int E, int T, int NBK) {
    __shared__ int cnt[256];
    const int tid = threadIdx.x;
    const int beg = blockIdx.x * CHUNK;
    const int end = min(beg + CHUNK, T);
    cnt[tid] = 0;
    __syncthreads();
    for (int i = beg + tid; i < end; i += 256) {
        int d = (i < E) ? dst[i] : (i - E);
        atomicAdd(&cnt[d >> 8], 1);
    }
    __syncthreads();
    if (tid < NBK && cnt[tid] > 0) atomicAdd(&bucketCount[tid], cnt[tid]);
}

__global__ void kb_scan(const int* __restrict__ bucketCount, int* bucketBase,
                        int* bucketCursor, int* row_ptr, int NBK, int N, int total) {
    __shared__ int sm[256];
    const int tid = threadIdx.x;
    int v = (tid < NBK) ? bucketCount[tid] : 0;
    sm[tid] = v;
    __syncthreads();
    for (int off = 1; off < 256; off <<= 1) {
        int t = (tid >= off) ? sm[tid - off] : 0;
        __syncthreads();
        sm[tid] += t;
        __syncthreads();
    }
    if (tid < NBK) {
        int ex = sm[tid] - v;
        bucketBase[tid] = ex;
        bucketCursor[tid] = ex;
    }
    if (tid == 0) {
        bucketBase[NBK] = total;
        row_ptr[N] = total;
    }
}

__global__ void kb_place(const int* __restrict__ src, const int* __restrict__ dst,
                         int* bucketCursor, unsigned* __restrict__ barr,
                         int E, int T, int NBK) {
    __shared__ int cnt[256];
    __shared__ int wb[256];
    const int tid = threadIdx.x;
    const int beg = blockIdx.x * CHUNK;
    const int end = min(beg + CHUNK, T);
    cnt[tid] = 0;
    __syncthreads();
    for (int i = beg + tid; i < end; i += 256) {
        int d = (i < E) ? dst[i] : (i - E);
        atomicAdd(&cnt[d >> 8], 1);
    }
    __syncthreads();
    if (tid < NBK) {
        int c = cnt[tid];
        wb[tid] = (c > 0) ? atomicAdd(&bucketCursor[tid], c) : 0;
    }
    __syncthreads();
    cnt[tid] = 0;
    __syncthreads();
    for (int i = beg + tid; i < end; i += 256) {
        int s, d;
        if (i < E) { s = src[i]; d = dst[i]; }
        else       { s = i - E;  d = s; }
        int g = d >> 8;
        unsigned pk = (unsigned)s | ((unsigned)(d & 255) << 16);
        int r = atomicAdd(&cnt[g], 1);
        barr[wb[g] + r] = pk;
    }
}

__global__ void kb_csr(const unsigned* __restrict__ barr, const int* __restrict__ bucketBase,
                       int* __restrict__ row_ptr, int* __restrict__ col, int N) {
    __shared__ int cnt[256];
    __shared__ int sm[256];
    __shared__ int cur[256];
    const int tid = threadIdx.x;
    const int b = blockIdx.x;
    const int beg = bucketBase[b];
    const int end = bucketBase[b + 1];
    cnt[tid] = 0;
    __syncthreads();
    for (int i = beg + tid; i < end; i += 256)
        atomicAdd(&cnt[barr[i] >> 16], 1);
    __syncthreads();
    int v = cnt[tid];
    sm[tid] = v;
    __syncthreads();
    for (int off = 1; off < 256; off <<= 1) {
        int t = (tid >= off) ? sm[tid - off] : 0;
        __syncthreads();
        sm[tid] += t;
        __syncthreads();
    }
    int ex = sm[tid] - v;
    int n = b * 256 + tid;
    if (n < N) row_ptr[n] = beg + ex;
    cur[tid] = beg + ex;
    __syncthreads();
    for (int i = beg + tid; i < end; i += 256) {
        unsigned p = barr[i];
        int pos = atomicAdd(&cur[p >> 16], 1);
        col[pos] = (int)(p & 0xFFFFu);
    }
}

// ---------------- MFMA GEMM: h = A @ W (fp32 in, bf16 out) + alpha epilogue ----
// mfma_f32_16x16x32_f16 with SWAPPED operands: A-op = W^T (from LDS), B-op = x
// rows (from global). Output D[c][m]: lane holds rows m=lane&15 (as D-col) and
// 4 CONSECUTIVE cols c = ct*16 + quad*4 + reg (as D-row) -> packed bf16 stores.
// fp16 input rounding (10-bit mantissa) keeps error ~3e-4 rms (vs 4.5e-3 thr).
__launch_bounds__(256)
__global__ void k_gemm(const float* __restrict__ A, const float* __restrict__ W,
                       const float* __restrict__ a_src, const float* __restrict__ a_dst,
                       unsigned* __restrict__ Hout,
                       float* __restrict__ asrc_o, float* __restrict__ adst_o,
                       int nrows, int ntiles) {
    __shared__ _Float16 Wt[128 * 136];  // [c][k], stride 136 (272B = 16*17, b128-aligned)
    const int tid = threadIdx.x;
    // stage W^T (fp32 [k][c] -> fp16 [c][k]), coalesced global reads
    for (int idx = tid; idx < 128 * 128 / 4; idx += 256) {
        int k = idx >> 5;            // 32 float4 per k-row
        int c4 = (idx & 31) * 4;
        float4 v = *(const float4*)&W[(size_t)k * 128 + c4];
        Wt[(c4 + 0) * 136 + k] = (_Float16)v.x;
        Wt[(c4 + 1) * 136 + k] = (_Float16)v.y;
        Wt[(c4 + 2) * 136 + k] = (_Float16)v.z;
        Wt[(c4 + 3) * 136 + k] = (_Float16)v.w;
    }
    __syncthreads();
    const int lane = tid & 63;
    const int m = lane & 15, quad = lane >> 4;

    // W fragments -> registers: wf[ks][ct] = A-op[mA=lane&15][k=quad*8+j]
    half8 wf[4][8];
#pragma unroll
    for (int ks = 0; ks < 4; ++ks)
#pragma unroll
        for (int ct = 0; ct < 8; ++ct)
            wf[ks][ct] = *(half8*)&Wt[(ct * 16 + m) * 136 + ks * 32 + quad * 8];

    const int wv = (blockIdx.x * 256 + tid) >> 6;
    const int nwaves = gridDim.x * 4;
    for (int t = wv; t < ntiles; t += nwaves) {
        const int row = t * 16 + m;
        const int rc = min(row, nrows - 1);
        const float* ap = A + (size_t)rc * 128;
        f32x4 acc[8];
#pragma unroll
        for (int ct = 0; ct < 8; ++ct) acc[ct] = (f32x4){0.f, 0.f, 0.f, 0.f};
#pragma unroll
        for (int ks = 0; ks < 4; ++ks) {
            float4 x0 = *(const float4*)&ap[ks * 32 + quad * 8];
            float4 x1 = *(const float4*)&ap[ks * 32 + quad * 8 + 4];
            half8 af;
            af[0] = (_Float16)x0.x; af[1] = (_Float16)x0.y;
            af[2] = (_Float16)x0.z; af[3] = (_Float16)x0.w;
            af[4] = (_Float16)x1.x; af[5] = (_Float16)x1.y;
            af[6] = (_Float16)x1.z; af[7] = (_Float16)x1.w;
#pragma unroll
            for (int ct = 0; ct < 8; ++ct)
                acc[ct] = __builtin_amdgcn_mfma_f32_16x16x32_f16(wf[ks][ct], af, acc[ct], 0, 0, 0);
        }
        // h store: lane's 4 consecutive cols per ct -> 2 packed uints
        if (row < nrows) {
#pragma unroll
            for (int ct = 0; ct < 8; ++ct) {
                uint2 o;
                o.x = pack_bf2(acc[ct][0], acc[ct][1]);
                o.y = pack_bf2(acc[ct][2], acc[ct][3]);
                *(uint2*)&Hout[(size_t)row * 64 + ct * 8 + quad * 2] = o;
            }
        }
        // alpha partials (fp32, pre-rounding); a_src/a_dst are L1-hot (512B)
        float ps[4] = {0.f, 0.f, 0.f, 0.f}, pd[4] = {0.f, 0.f, 0.f, 0.f};
#pragma unroll
        for (int ct = 0; ct < 8; ++ct) {
            int hh = ct >> 1;
#pragma unroll
            for (int r = 0; r < 4; ++r) {
                int c = ct * 16 + quad * 4 + r;
                ps[hh] += acc[ct][r] * a_src[c];
                pd[hh] += acc[ct][r] * a_dst[c];
            }
        }
#pragma unroll
        for (int hh = 0; hh < 4; ++hh) {
            ps[hh] += __shfl_xor(ps[hh], 16); ps[hh] += __shfl_xor(ps[hh], 32);
            pd[hh] += __shfl_xor(pd[hh], 16); pd[hh] += __shfl_xor(pd[hh], 32);
        }
        if (row < nrows) {
            asrc_o[(size_t)row * 4 + quad] = ps[quad];
            adst_o[(size_t)row * 4 + quad] = pd[quad];
        }
    }
}

// ---------------- fused softmax-aggregate + bias + ELU (unchanged R5) ----------
#define BAT 16
__launch_bounds__(256)
__global__ void k_aggr(const unsigned* __restrict__ h,
                       const float* __restrict__ asrc, const float* __restrict__ adst,
                       const float* __restrict__ bias,
                       const int* __restrict__ row_ptr, const int* __restrict__ col,
                       float* __restrict__ out, int N) {
    const int lane = threadIdx.x & 63;
    const int d = blockIdx.x * 4 + (threadIdx.x >> 6);
    if (d >= N) return;
    const int eb  = lane >> 2;
    const int hp  = lane & 3;
    const int hdc = lane >> 4;
    const float adv = adst[(size_t)d * 4 + hp];
    const int beg = row_ptr[d];
    const int end = row_ptr[d + 1];

    float ac0 = 0.f, ac1 = 0.f, sp = 0.f;
    int cv = 0;
    { int idx = beg + eb; if (idx < end) cv = col[idx]; }

    for (int j = beg; j < end; j += BAT) {
        int cvn = 0;
        { int idx = j + BAT + eb; if (idx < end) cvn = col[idx]; }

        float a = asrc[(size_t)(unsigned)cv * 4 + hp];
        float p = (j + eb < end) ? pfun(a + adv) : 0.f;
        sp += p;

        unsigned u[BAT];
#pragma unroll
        for (int k = 0; k < BAT; ++k) {
            int sk = __builtin_amdgcn_readlane(cv, 4 * k);
            u[k] = h[(size_t)(unsigned)sk * 64 + lane];
        }
#pragma unroll
        for (int k = 0; k < BAT; ++k) {
            float pk = __shfl(p, 4 * k + hdc);
            ac0 += pk * bf2f_lo(u[k]);
            ac1 += pk * bf2f_hi(u[k]);
        }
        cv = cvn;
    }

    sp += __shfl_xor(sp, 4);
    sp += __shfl_xor(sp, 8);
    sp += __shfl_xor(sp, 16);
    sp += __shfl_xor(sp, 32);
    float spv = __shfl(sp, hdc);
    float inv = 1.f / spv;

    int c = 2 * lane;
    float v0 = ac0 * inv + bias[c];
    float v1 = ac1 * inv + bias[c + 1];
    v0 = (v0 > 0.f) ? v0 : (__expf(v0) - 1.f);
    v1 = (v1 > 0.f) ? v1 : (__expf(v1) - 1.f);
    *(float2*)&out[(size_t)d * 128 + c] = make_float2(v0, v1);
}

// ---------------- launch ----------------
extern "C" void kernel_launch(void* const* d_in, const int* in_sizes, int n_in,
                              void* d_out, int out_size, void* d_ws, size_t ws_size,
                              hipStream_t stream) {
    const float* x      = (const float*)d_in[0];
    const int*   ei     = (const int*)d_in[1];
    const float* W1     = (const float*)d_in[2];
    const float* a_src1 = (const float*)d_in[3];
    const float* a_dst1 = (const float*)d_in[4];
    const float* b1     = (const float*)d_in[5];
    const float* W2     = (const float*)d_in[6];
    const float* a_src2 = (const float*)d_in[7];
    const float* a_dst2 = (const float*)d_in[8];
    const float* b2     = (const float*)d_in[9];

    const int N = in_sizes[0] / 128;
    const int E = in_sizes[1] / 2;
    const int T = E + N;
    const int NBK = (N + 255) / 256;
    const int* src = ei;
    const int* dst = ei + E;

    char* w = (char*)d_ws;
    auto alloc = [&](size_t bytes) -> char* {
        char* p = w;
        w += (bytes + 255) & ~(size_t)255;
        return p;
    };
    unsigned* h_bf    = (unsigned*)alloc((size_t)N * 64 * 4);
    float*    o1      = (float*)alloc((size_t)N * 128 * 4);
    float*    asrc    = (float*)alloc((size_t)N * 4 * 4);
    float*    adst    = (float*)alloc((size_t)N * 4 * 4);
    int*      row_ptr = (int*)alloc((size_t)(N + 1) * 4);
    int*      col     = (int*)alloc((size_t)T * 4);
    int*      bCount  = (int*)alloc((size_t)NBK * 4);
    int*      bBase   = (int*)alloc((size_t)(NBK + 1) * 4);
    int*      bCursor = (int*)alloc((size_t)NBK * 4);
    unsigned* barr    = (unsigned*)o1;   // alias: dead before o1 written
    (void)ws_size; (void)n_in; (void)out_size;

    const int PB = (T + CHUNK - 1) / CHUNK;

    hipLaunchKernelGGL(kb_zero, dim3((NBK + 255) / 256), dim3(256), 0, stream, bCount, NBK);
    hipLaunchKernelGGL(kb_count, dim3(PB), dim3(256), 0, stream, dst, bCount, E, T, NBK);
    hipLaunchKernelGGL(kb_scan, dim3(1), dim3(256), 0, stream, bCount, bBase, bCursor, row_ptr, NBK, N, T);
    hipLaunchKernelGGL(kb_place, dim3(PB), dim3(256), 0, stream, src, dst, bCursor, barr, E, T, NBK);
    hipLaunchKernelGGL(kb_csr, dim3(NBK), dim3(256), 0, stream, barr, bBase, row_ptr, col, N);

    const int ntiles = (N + 15) / 16;
    const int GB = 512;               // grid-stride over tiles (2048 waves)
    const int AB = (N + 3) / 4;

    hipLaunchKernelGGL(k_gemm, dim3(GB), dim3(256), 0, stream, x, W1, a_src1, a_dst1, h_bf, asrc, adst, N, ntiles);
    hipLaunchKernelGGL(k_aggr, dim3(AB), dim3(256), 0, stream, h_bf, asrc, adst, b1, row_ptr, col, o1, N);
    hipLaunchKernelGGL(k_gemm, dim3(GB), dim3(256), 0, stream, o1, W2, a_src2, a_dst2, h_bf, asrc, adst, N, ntiles);
    hipLaunchKernelGGL(k_aggr, dim3(AB), dim3(256), 0, stream, h_bf, asrc, adst, b2, row_ptr, col, (float*)d_out, N);
}